// Round 1
// baseline (23.982 us; speedup 1.0000x reference)
//
#include <hip/hip_runtime.h>

// Problem constants
#define D1 128
#define D2 128
#define XC 64           // x columns (embedded into even grid columns)
#define BATCH 32
#define NLAYERS 4
#define SIG_PER_LAYER (16 * D1 * D2)       // 262144 floats per layer
#define STATE_ELEMS (BATCH * D1 * D2)      // 524288 floats
#define OUT_ELEMS (BATCH * D1 * XC)        // 262144 floats

// ---------------------------------------------------------------------------
// sigmoid(toggle_gates) -> ws, vectorized float4. n = 4*262144 floats = 262144 float4s
__global__ __launch_bounds__(256) void sig_kernel(const float4* __restrict__ g,
                                                  float4* __restrict__ s) {
    int i = blockIdx.x * 256 + threadIdx.x;
    float4 v = g[i];
    float4 r;
    r.x = 1.0f / (1.0f + __expf(-v.x));
    r.y = 1.0f / (1.0f + __expf(-v.y));
    r.z = 1.0f / (1.0f + __expf(-v.z));
    r.w = 1.0f / (1.0f + __expf(-v.w));
    s[i] = r;
}

// ---------------------------------------------------------------------------
// One layer. FIRST: input is x (B,128,64), grid state is x embedded at even
// columns, zeros at odd. LAST: compute only even columns, write (B,128,64).
// Sum over 16 combos == multilinear interp of the 16 sigmoid(gate) values at
// (f0,f1,f2,f3): 15-lerp tree, b3 (LSB of m) pairs with f3.
template <int FIRST, int LAST>
__global__ __launch_bounds__(256) void layer_kernel(const float* __restrict__ in,
                                                    const float* __restrict__ sig,
                                                    float* __restrict__ out) {
    int idx = blockIdx.x * 256 + threadIdx.x;

    int p2, p1, b;
    if (LAST) {
        int p2c = idx & (XC - 1);       // even-output column index
        p1 = (idx >> 6) & (D1 - 1);
        b  = idx >> 13;
        p2 = p2c << 1;
    } else {
        p2 = idx & (D2 - 1);
        p1 = (idx >> 7) & (D1 - 1);
        b  = idx >> 14;
    }
    int p1n = (p1 + 1) & (D1 - 1);
    int p2n = (p2 + 1) & (D2 - 1);

    // Gather the 2x2 periodic window: f_j, j = i1*2 + i2
    float f0, f1, f2, f3;
    if (FIRST) {
        const float* xr  = in + ((size_t)b * D1 + p1)  * XC;
        const float* xrn = in + ((size_t)b * D1 + p1n) * XC;
        if ((p2 & 1) == 0) {            // this col holds x, right neighbor is 0
            f0 = xr[p2 >> 1];  f1 = 0.0f;
            f2 = xrn[p2 >> 1]; f3 = 0.0f;
        } else {                        // this col is 0, right neighbor holds x
            f0 = 0.0f; f1 = xr[p2n >> 1];
            f2 = 0.0f; f3 = xrn[p2n >> 1];
        }
    } else {
        const float* sr  = in + ((size_t)b * D1 + p1)  * D2;
        const float* srn = in + ((size_t)b * D1 + p1n) * D2;
        f0 = sr[p2];  f1 = sr[p2n];
        f2 = srn[p2]; f3 = srn[p2n];
    }

    // 16 gate values for this cell (stride 16384 floats between combo planes)
    const float* t = sig + (size_t)p1 * D2 + p2;
    float tv[16];
#pragma unroll
    for (int m = 0; m < 16; ++m) tv[m] = t[(size_t)m * (D1 * D2)];

    // multilinear interp: reduce b3 (f3), b2 (f2), b1 (f1), b0 (f0)
    float u[8];
#pragma unroll
    for (int k = 0; k < 8; ++k) u[k] = fmaf(f3, tv[2 * k + 1] - tv[2 * k], tv[2 * k]);
    float v[4];
#pragma unroll
    for (int k = 0; k < 4; ++k) v[k] = fmaf(f2, u[2 * k + 1] - u[2 * k], u[2 * k]);
    float w2[2];
#pragma unroll
    for (int k = 0; k < 2; ++k) w2[k] = fmaf(f1, v[2 * k + 1] - v[2 * k], v[2 * k]);
    float r = fmaf(f0, w2[1] - w2[0], w2[0]);

    r = fminf(fmaxf(r, 0.0f), 1.0f);

    if (LAST) {
        out[((size_t)b * D1 + p1) * XC + (p2 >> 1)] = r;
    } else {
        out[((size_t)b * D1 + p1) * D2 + p2] = r;
    }
}

// ---------------------------------------------------------------------------
extern "C" void kernel_launch(void* const* d_in, const int* in_sizes, int n_in,
                              void* d_out, int out_size, void* d_ws, size_t ws_size,
                              hipStream_t stream) {
    const float* x  = (const float*)d_in[0];               // (32,128,64)
    const float* tg = (const float*)d_in[1];               // (4,16,128,128)
    float* out = (float*)d_out;                            // (32,128,64)

    float* ws  = (float*)d_ws;
    float* sig = ws;                                       // 4*262144 floats (4 MB)
    float* sA  = ws + NLAYERS * SIG_PER_LAYER;             // 524288 floats (2 MB)
    float* sB  = sA + STATE_ELEMS;                         // 524288 floats (2 MB)

    // sigmoid of all gates: 1048576 floats = 262144 float4 -> 1024 blocks
    sig_kernel<<<1024, 256, 0, stream>>>((const float4*)tg, (float4*)sig);

    // layer 0: embed-from-x -> sA
    layer_kernel<1, 0><<<STATE_ELEMS / 256, 256, 0, stream>>>(x, sig + 0 * SIG_PER_LAYER, sA);
    // layer 1: sA -> sB
    layer_kernel<0, 0><<<STATE_ELEMS / 256, 256, 0, stream>>>(sA, sig + 1 * SIG_PER_LAYER, sB);
    // layer 2: sB -> sA
    layer_kernel<0, 0><<<STATE_ELEMS / 256, 256, 0, stream>>>(sB, sig + 2 * SIG_PER_LAYER, sA);
    // layer 3: even columns only -> out
    layer_kernel<0, 1><<<OUT_ELEMS / 256, 256, 0, stream>>>(sA, sig + 3 * SIG_PER_LAYER, out);
}

// Round 2
// 21.277 us; speedup vs baseline: 1.1271x; 1.1271x over previous
//
#include <hip/hip_runtime.h>

// Problem constants
#define D1 128
#define D2 128
#define XC 64            // x columns (embedded into even grid columns)
#define BATCH 32
#define T 8              // output tile edge
#define HALO 4           // 4 layers x 1-cell one-sided halo
#define REG 12           // T + HALO : input region edge
#define NB 8             // batches per block
#define NBG (BATCH / NB) // 4 batch groups
#define NTILES 256       // (128/8)^2
#define NTHREADS 256

__device__ __forceinline__ float sigmoidf_(float v) {
    return __fdividef(1.0f, 1.0f + __expf(-v));
}

// Multilinear interp of 16 gate values at (f0,f1,f2,f3).
// m = b0*8 + b1*4 + b2*2 + b3; b_j pairs with f_j; reduce LSB (b3/f3) first.
__device__ __forceinline__ float interp16(const float* __restrict__ g, int c, int SS,
                                          float f0, float f1, float f2, float f3) {
    float t[16];
#pragma unroll
    for (int m = 0; m < 16; ++m) t[m] = g[m * SS + c];
    float u[8];
#pragma unroll
    for (int k = 0; k < 8; ++k) u[k] = fmaf(f3, t[2 * k + 1] - t[2 * k], t[2 * k]);
    float v[4];
#pragma unroll
    for (int k = 0; k < 4; ++k) v[k] = fmaf(f2, u[2 * k + 1] - u[2 * k], u[2 * k]);
    float w[2];
#pragma unroll
    for (int k = 0; k < 2; ++k) w[k] = fmaf(f1, v[2 * k + 1] - v[2 * k], v[2 * k]);
    float r = fmaf(f0, w[1] - w[0], w[0]);
    return fminf(fmaxf(r, 0.0f), 1.0f);
}

// Stage layer L's gates (region S x S at tile origin) into LDS, sigmoided.
template <int S, int L>
__device__ __forceinline__ void load_gates(int tid, int t1, int t2,
                                           const float* __restrict__ tg,
                                           float* __restrict__ g_lds) {
    constexpr int SS = S * S;
    const float* gl = tg + (size_t)L * 16 * D1 * D2;
    for (int idx = tid; idx < 16 * SS; idx += NTHREADS) {
        int m = idx / SS;
        int c = idx - m * SS;
        int q1 = c / S;
        int q2 = c - q1 * S;
        int p1 = (t1 + q1) & (D1 - 1);
        int p2 = (t2 + q2) & (D2 - 1);
        g_lds[m * SS + c] = sigmoidf_(gl[(m << 14) + (p1 << 7) + p2]);
    }
}

// Generic (non-last) layer: region S x S for all NB batches, st_in -> st_out.
// State buffers use REG stride throughout.
template <int S>
__device__ __forceinline__ void compute_layer(int tid,
                                              const float* __restrict__ st_in,
                                              float* __restrict__ st_out,
                                              const float* __restrict__ g_lds) {
    constexpr int SS = S * S;
    for (int idx = tid; idx < NB * SS; idx += NTHREADS) {
        int b  = idx / SS;
        int c  = idx - b * SS;
        int q1 = c / S;
        int q2 = c - q1 * S;
        const float* sb = st_in + b * (REG * REG);
        int base = q1 * REG + q2;
        float f0 = sb[base],       f1 = sb[base + 1];
        float f2 = sb[base + REG], f3 = sb[base + REG + 1];
        float r  = interp16(g_lds, c, SS, f0, f1, f2, f3);
        st_out[b * (REG * REG) + base] = r;
    }
}

__global__ __launch_bounds__(NTHREADS) void fused_kernel(const float* __restrict__ x,
                                                         const float* __restrict__ tg,
                                                         float* __restrict__ out) {
    __shared__ float g_lds[16 * 11 * 11];        // <= 16*121 floats (7.7 KB)
    __shared__ float st[2][NB * REG * REG];      // ping-pong state (9.2 KB)

    int tid  = threadIdx.x;
    int bid  = blockIdx.x;
    int bg   = bid >> 8;                 // batch group (0..3)
    int tile = bid & (NTILES - 1);
    int t1   = ((tile >> 4) & 15) << 3;  // tile origin row
    int t2   = (tile & 15) << 3;         // tile origin col (even)

    const float* xb = x + (size_t)(bg * NB) * D1 * XC;

    // Stage input region: even grid columns hold x, odd are zero.
    for (int idx = tid; idx < NB * REG * REG; idx += NTHREADS) {
        int b  = idx / (REG * REG);
        int c  = idx - b * (REG * REG);
        int q1 = c / REG;
        int q2 = c - q1 * REG;
        int p1 = (t1 + q1) & (D1 - 1);
        int p2 = (t2 + q2) & (D2 - 1);
        float v = 0.0f;
        if (!(p2 & 1)) v = xb[(b * D1 + p1) * XC + (p2 >> 1)];
        st[0][idx] = v;
    }
    load_gates<11, 0>(tid, t1, t2, tg, g_lds);   // no barrier needed vs input stage
    __syncthreads();
    compute_layer<11>(tid, st[0], st[1], g_lds);
    __syncthreads();

    load_gates<10, 1>(tid, t1, t2, tg, g_lds);
    __syncthreads();
    compute_layer<10>(tid, st[1], st[0], g_lds);
    __syncthreads();

    load_gates<9, 2>(tid, t1, t2, tg, g_lds);
    __syncthreads();
    compute_layer<9>(tid, st[0], st[1], g_lds);
    __syncthreads();

    load_gates<8, 3>(tid, t1, t2, tg, g_lds);
    __syncthreads();

    // Last layer: only even columns of the 8x8 tile -> out. NB*8*4 = 256 = one per thread.
    {
        int b   = tid >> 5;              // batch within group
        int c   = tid & 31;
        int q1  = c >> 2;
        int q2  = (c & 3) << 1;          // even column within tile
        const float* sb = st[1] + b * (REG * REG);
        int base = q1 * REG + q2;
        float f0 = sb[base],       f1 = sb[base + 1];
        float f2 = sb[base + REG], f3 = sb[base + REG + 1];
        int gc = q1 * 8 + q2;
        float r = interp16(g_lds, gc, 64, f0, f1, f2, f3);
        int p1 = t1 + q1;                // < 128, no wrap
        int p2 = t2 + q2;                // even
        out[((size_t)(bg * NB + b) * D1 + p1) * XC + (p2 >> 1)] = r;
    }
}

extern "C" void kernel_launch(void* const* d_in, const int* in_sizes, int n_in,
                              void* d_out, int out_size, void* d_ws, size_t ws_size,
                              hipStream_t stream) {
    const float* x  = (const float*)d_in[0];   // (32,128,64)
    const float* tg = (const float*)d_in[1];   // (4,16,128,128)
    float* out = (float*)d_out;                // (32,128,64)

    fused_kernel<<<NBG * NTILES, NTHREADS, 0, stream>>>(x, tg, out);
}

// Round 3
// 15.386 us; speedup vs baseline: 1.5587x; 1.3829x over previous
//
#include <hip/hip_runtime.h>

// Problem constants
#define D1 128
#define D2 128
#define XC 64
#define NBH 16              // batches per block (32 total / 2 halves)
#define RS 16               // LDS row stride (pow2)
#define RR 12               // staged region edge: 8 (tile) + 4 (halo)
#define BSTR (RR * RS)      // 192 floats per batch plane
#define B1 (NBH * BSTR)     // 3072: ping-pong buffer offset
#define NTH 192
#define PLANE 16384         // floats per gate combo plane (128*128)

__device__ __forceinline__ float fast_sigmoid(float v) {
    return __builtin_amdgcn_rcpf(1.0f + __expf(-v));   // |rel err| ~1e-7, fine vs 1.4e-2
}
__device__ __forceinline__ float clamp01(float r) {
    return fminf(fmaxf(r, 0.0f), 1.0f);
}

// Full 16-gate multilinear interp layer: st[src] -> st[dst] for this thread's cell.
__device__ __forceinline__ void compute_layer(float* __restrict__ st, int src, int dst,
                                              int sbase, const float g[16]) {
    float d[8];
#pragma unroll
    for (int k = 0; k < 8; ++k) d[k] = g[2 * k + 1] - g[2 * k];   // batch-invariant deltas
#pragma unroll
    for (int b = 0; b < NBH; ++b) {
        const float* sb = st + src + b * BSTR + sbase;
        const float f0 = sb[0], f1 = sb[1], f2 = sb[RS], f3 = sb[RS + 1];
        float u[8];
#pragma unroll
        for (int k = 0; k < 8; ++k) u[k] = fmaf(f3, d[k], g[2 * k]);
        float v[4];
#pragma unroll
        for (int k = 0; k < 4; ++k) v[k] = fmaf(f2, u[2 * k + 1] - u[2 * k], u[2 * k]);
        float w[2];
#pragma unroll
        for (int k = 0; k < 2; ++k) w[k] = fmaf(f1, v[2 * k + 1] - v[2 * k], v[2 * k]);
        st[dst + b * BSTR + sbase] = clamp01(fmaf(f0, w[1] - w[0], w[0]));
    }
}

__global__ __launch_bounds__(NTH) void fused_kernel(const float* __restrict__ x,
                                                    const float* __restrict__ tg,
                                                    float* __restrict__ out) {
    __shared__ float st[2 * B1 + 64];    // ping-pong state + pad for harmless edge reads

    const int tid  = threadIdx.x;
    const int tile = blockIdx.x & 255;
    const int b0   = (blockIdx.x >> 8) * NBH;    // batch offset of this half

    const int q1 = tid >> 4;             // 0..11
    const int q2 = tid & 15;             // 0..15
    const bool act = (q2 < RR);

    const int t1 = ((tile >> 4) & 15) << 3;
    const int t2 = (tile & 15) << 3;
    const int p1 = (t1 + q1) & (D1 - 1);
    const int p2 = (t2 + q2) & (D2 - 1);
    const int sbase = (q1 << 4) | q2;
    const int modd = p2 & 1;             // == q2&1 since t2 is even
    const float* gcell = tg + (p1 << 7) + p2;

    // ---- stage input region into st[0]: even columns hold x, odd are zero ----
    if (act) {
        if (!modd) {
            const float* xp = x + ((size_t)b0 * D1 + p1) * XC + (p2 >> 1);
#pragma unroll
            for (int b = 0; b < NBH; ++b)
                st[b * BSTR + sbase] = xp[(size_t)b * (D1 * XC)];
        } else {
#pragma unroll
            for (int b = 0; b < NBH; ++b)
                st[b * BSTR + sbase] = 0.0f;
        }
    }

    // ---- layer-0 gates: parity-reduced bilerp needs only 4 of 16 combos ----
    // even p2 (f1=f3=0): m = b0*8 + b2*2 in {0,2,8,10}; inner lerp over f2, outer f0
    // odd  p2 (f0=f2=0): m = b1*4 + b3   in {0,1,4,5};  inner lerp over f3, outer f1
    float g0[4];
    float graw[16];
    if (act) {
#pragma unroll
        for (int j = 0; j < 4; ++j) {
            const int m = modd ? ((j >> 1) * 4 + (j & 1)) : ((j >> 1) * 8 + (j & 1) * 2);
            g0[j] = gcell[(size_t)m * PLANE];
        }
#pragma unroll
        for (int j = 0; j < 4; ++j) g0[j] = fast_sigmoid(g0[j]);
        // prefetch layer-1 raw gates (consumed after next barrier)
#pragma unroll
        for (int m = 0; m < 16; ++m) graw[m] = gcell[(size_t)(16 + m) * PLANE];
    }
    __syncthreads();

    // ---- layer 0: st[0] -> st[B1] ----
    if (act) {
        const float d10 = g0[1] - g0[0], d32 = g0[3] - g0[2];
#pragma unroll
        for (int b = 0; b < NBH; ++b) {
            const float* sb = st + b * BSTR + sbase;
            const float f0 = sb[0], f1 = sb[1], f2 = sb[RS], f3 = sb[RS + 1];
            const float fin  = modd ? f3 : f2;
            const float fout = modd ? f1 : f0;
            const float a = fmaf(fin, d10, g0[0]);
            const float c = fmaf(fin, d32, g0[2]);
            st[B1 + b * BSTR + sbase] = clamp01(fmaf(fout, c - a, a));
        }
    }
    __syncthreads();

    // ---- layer 1: st[B1] -> st[0], prefetch layer-2 gates ----
    float g[16];
    if (act) {
#pragma unroll
        for (int m = 0; m < 16; ++m) g[m] = fast_sigmoid(graw[m]);
#pragma unroll
        for (int m = 0; m < 16; ++m) graw[m] = gcell[(size_t)(32 + m) * PLANE];
        compute_layer(st, B1, 0, sbase, g);
    }
    __syncthreads();

    // ---- layer 2: st[0] -> st[B1], prefetch layer-3 gates (final threads only) ----
    const bool fact = act && (q1 < 8) && (q2 < 8) && !(q2 & 1);
    if (act) {
#pragma unroll
        for (int m = 0; m < 16; ++m) g[m] = fast_sigmoid(graw[m]);
        if (fact) {
#pragma unroll
            for (int m = 0; m < 16; ++m) graw[m] = gcell[(size_t)(48 + m) * PLANE];
        }
        compute_layer(st, 0, B1, sbase, g);
    }
    __syncthreads();

    // ---- layer 3: only even columns of the 8x8 tile -> out ----
    if (fact) {
#pragma unroll
        for (int m = 0; m < 16; ++m) g[m] = fast_sigmoid(graw[m]);
        float d[8];
#pragma unroll
        for (int k = 0; k < 8; ++k) d[k] = g[2 * k + 1] - g[2 * k];
        float* op = out + ((size_t)b0 * D1 + p1) * XC + (p2 >> 1);
#pragma unroll
        for (int b = 0; b < NBH; ++b) {
            const float* sb = st + B1 + b * BSTR + sbase;
            const float f0 = sb[0], f1 = sb[1], f2 = sb[RS], f3 = sb[RS + 1];
            float u[8];
#pragma unroll
            for (int k = 0; k < 8; ++k) u[k] = fmaf(f3, d[k], g[2 * k]);
            float v[4];
#pragma unroll
            for (int k = 0; k < 4; ++k) v[k] = fmaf(f2, u[2 * k + 1] - u[2 * k], u[2 * k]);
            float w[2];
#pragma unroll
            for (int k = 0; k < 2; ++k) w[k] = fmaf(f1, v[2 * k + 1] - v[2 * k], v[2 * k]);
            op[(size_t)b * (D1 * XC)] = clamp01(fmaf(f0, w[1] - w[0], w[0]));
        }
    }
}

extern "C" void kernel_launch(void* const* d_in, const int* in_sizes, int n_in,
                              void* d_out, int out_size, void* d_ws, size_t ws_size,
                              hipStream_t stream) {
    const float* x  = (const float*)d_in[0];   // (32,128,64)
    const float* tg = (const float*)d_in[1];   // (4,16,128,128)
    float* out = (float*)d_out;                // (32,128,64)

    fused_kernel<<<512, NTH, 0, stream>>>(x, tg, out);
}